// Round 1
// baseline (21075.851 us; speedup 1.0000x reference)
//
#include <hip/hip_runtime.h>
#include <math.h>

#define BB 32
#define SS 48
#define HH 1024
#define EE 256
#define VOC 32000
#define GEN 32
#define G3 3072

__device__ __forceinline__ float sigf(float x) { return 1.f / (1.f + expf(-x)); }

// ---------------- embedding for encoder input ----------------
__global__ __launch_bounds__(256) void embed_en_k(const int* __restrict__ inputs,
                                                  const float* __restrict__ emb,
                                                  float* __restrict__ x) {
    int i = blockIdx.x * 256 + threadIdx.x;   // < BB*SS*EE
    int row = i >> 8;                          // b*SS+s
    int e = i & 255;
    x[i] = emb[(size_t)inputs[row] * EE + e];
}

// ---------------- tiled fp32 GEMM: C[M,N] = A[M,K]@B[K,N] + bias[N] ----------------
// BM=BN=64, BK=16, 256 threads, 4x4 micro-tile
__global__ __launch_bounds__(256) void gemm_tiled(const float* __restrict__ A,
                                                  const float* __restrict__ Bm,
                                                  const float* __restrict__ bias,
                                                  float* __restrict__ C,
                                                  int M, int N, int K) {
    __shared__ float As[16][65];
    __shared__ float Bs[16][65];
    int tid = threadIdx.x;
    int tx = tid & 15, ty = tid >> 4;
    int arow = blockIdx.y * 64, bcol = blockIdx.x * 64;
    float acc[4][4] = {};
    for (int k0 = 0; k0 < K; k0 += 16) {
        {
            int m = tid >> 2, kk = (tid & 3) << 2;
            float4 v = *(const float4*)(A + (size_t)(arow + m) * K + k0 + kk);
            As[kk + 0][m] = v.x; As[kk + 1][m] = v.y;
            As[kk + 2][m] = v.z; As[kk + 3][m] = v.w;
        }
        {
            int kk = tid >> 4, n = (tid & 15) << 2;
            float4 v = *(const float4*)(Bm + (size_t)(k0 + kk) * N + bcol + n);
            Bs[kk][n] = v.x; Bs[kk][n + 1] = v.y; Bs[kk][n + 2] = v.z; Bs[kk][n + 3] = v.w;
        }
        __syncthreads();
#pragma unroll
        for (int kk = 0; kk < 16; ++kk) {
            float a[4], b[4];
#pragma unroll
            for (int i = 0; i < 4; ++i) a[i] = As[kk][ty * 4 + i];
#pragma unroll
            for (int j = 0; j < 4; ++j) b[j] = Bs[kk][tx * 4 + j];
#pragma unroll
            for (int i = 0; i < 4; ++i)
#pragma unroll
                for (int j = 0; j < 4; ++j) acc[i][j] += a[i] * b[j];
        }
        __syncthreads();
    }
#pragma unroll
    for (int i = 0; i < 4; ++i) {
        int row = arow + ty * 4 + i;
#pragma unroll
        for (int j = 0; j < 4; ++j) {
            int col = bcol + tx * 4 + j;
            C[(size_t)row * N + col] = acc[i][j] + bias[col];
        }
    }
}

// ---------------- fused encoder GRU step ----------------
// gh = h_prev @ U + b1 (gate-grouped columns), then GRU pointwise with
// precomputed gi (= x@W + b0). Grid: HH/8 = 128 blocks; 384 threads.
__global__ __launch_bounds__(384) void enc_gru_step(const float* __restrict__ gi,
                                                    const float* __restrict__ U,
                                                    const float* __restrict__ b1,
                                                    const float* __restrict__ hin,
                                                    float* __restrict__ hout,
                                                    float* __restrict__ seqout,
                                                    int t) {
    __shared__ float part[2][24][33];
    int tid = threadIdx.x;
    int col24 = tid % 24;
    int mg = (tid / 24) & 7;
    int ks = tid / 192;           // 0..1
    int gate = col24 >> 3, c8 = col24 & 7;
    int cglob = blockIdx.x * 8 + c8;
    int bcol = gate * HH + cglob;
    const float* A0 = hin + (size_t)(mg * 4 + 0) * HH;
    const float* A1 = A0 + HH;
    const float* A2 = A1 + HH;
    const float* A3 = A2 + HH;
    const float* Up = U + bcol;
    float a0 = 0, a1 = 0, a2 = 0, a3 = 0;
    int kend = ks * 512 + 512;
#pragma unroll 4
    for (int k = ks * 512; k < kend; ++k) {
        float bv = Up[(size_t)k * G3];
        a0 += A0[k] * bv; a1 += A1[k] * bv; a2 += A2[k] * bv; a3 += A3[k] * bv;
    }
    part[ks][col24][mg * 4 + 0] = a0;
    part[ks][col24][mg * 4 + 1] = a1;
    part[ks][col24][mg * 4 + 2] = a2;
    part[ks][col24][mg * 4 + 3] = a3;
    __syncthreads();
    if (tid < 256) {
        int m = tid >> 3, c8b = tid & 7;
        int cg = blockIdx.x * 8 + c8b;
        float ghz = part[0][c8b][m]      + part[1][c8b][m]      + b1[cg];
        float ghr = part[0][8 + c8b][m]  + part[1][8 + c8b][m]  + b1[HH + cg];
        float ghh = part[0][16 + c8b][m] + part[1][16 + c8b][m] + b1[2 * HH + cg];
        const float* girow = gi + (size_t)(m * SS + t) * G3;
        float giz = girow[cg], gir = girow[HH + cg], gih = girow[2 * HH + cg];
        float hp = hin[m * HH + cg];
        float z = sigf(giz + ghz);
        float r = sigf(gir + ghr);
        float nn = tanhf(gih + r * ghh);
        float h = z * hp + (1.f - z) * nn;
        hout[m * HH + cg] = h;
        seqout[(size_t)(m * SS + t) * HH + cg] = h;
    }
}

// ---------------- fused decoder GRU (zero initial state) ----------------
// gi = A@W + b0 (gate-grouped), gh = b1 const, h = (1-z)*n.
// Grid: HH/8 = 128 blocks; 768 threads = 24 cols x 8 mg x 4 ksplit.
__global__ __launch_bounds__(768) void dec_gru_fused(const float* __restrict__ A,
                                                     int K,
                                                     const float* __restrict__ W,
                                                     const float* __restrict__ b0,
                                                     const float* __restrict__ b1,
                                                     float* __restrict__ hout) {
    __shared__ float part[4][24][33];
    int tid = threadIdx.x;
    int col24 = tid % 24;
    int mg = (tid / 24) & 7;
    int ks = tid / 192;           // 0..3
    int gate = col24 >> 3, c8 = col24 & 7;
    int cglob = blockIdx.x * 8 + c8;
    int bcol = gate * HH + cglob;
    int kslice = K >> 2;
    const float* A0 = A + (size_t)(mg * 4 + 0) * K;
    const float* A1 = A0 + K;
    const float* A2 = A1 + K;
    const float* A3 = A2 + K;
    const float* Wp = W + bcol;
    float a0 = 0, a1 = 0, a2 = 0, a3 = 0;
    int kend = (ks + 1) * kslice;
#pragma unroll 4
    for (int k = ks * kslice; k < kend; ++k) {
        float bv = Wp[(size_t)k * G3];
        a0 += A0[k] * bv; a1 += A1[k] * bv; a2 += A2[k] * bv; a3 += A3[k] * bv;
    }
    part[ks][col24][mg * 4 + 0] = a0;
    part[ks][col24][mg * 4 + 1] = a1;
    part[ks][col24][mg * 4 + 2] = a2;
    part[ks][col24][mg * 4 + 3] = a3;
    __syncthreads();
    if (tid < 256) {
        int m = tid >> 3, c8b = tid & 7;
        int cg = blockIdx.x * 8 + c8b;
        float giz = part[0][c8b][m] + part[1][c8b][m] + part[2][c8b][m] + part[3][c8b][m]
                    + b0[cg];
        float gir = part[0][8 + c8b][m] + part[1][8 + c8b][m] + part[2][8 + c8b][m]
                    + part[3][8 + c8b][m] + b0[HH + cg];
        float gih = part[0][16 + c8b][m] + part[1][16 + c8b][m] + part[2][16 + c8b][m]
                    + part[3][16 + c8b][m] + b0[2 * HH + cg];
        float z = sigf(giz + b1[cg]);
        float r = sigf(gir + b1[HH + cg]);
        float nn = tanhf(gih + r * b1[2 * HH + cg]);
        hout[m * HH + cg] = (1.f - z) * nn;
    }
}

// ---------------- small-M (M=32) GEMM: C = A[32,K]@B[K,N] + bias ----------------
// 256 threads: 32 cols x 8 m-groups (4 m each). Grid: N/32 blocks.
__global__ __launch_bounds__(256) void gemm_smallM(const float* __restrict__ A,
                                                   const float* __restrict__ Bm,
                                                   const float* __restrict__ bias,
                                                   float* __restrict__ C,
                                                   int K, int N, int ldc) {
    int tid = threadIdx.x;
    int c = tid & 31, mg = tid >> 5;
    int n = blockIdx.x * 32 + c;
    const float* A0 = A + (size_t)(mg * 4 + 0) * K;
    const float* A1 = A0 + K;
    const float* A2 = A1 + K;
    const float* A3 = A2 + K;
    const float* Bp = Bm + n;
    float s0 = 0, s1 = 0, s2 = 0, s3 = 0;
#pragma unroll 4
    for (int k = 0; k < K; ++k) {
        float bv = Bp[(size_t)k * N];
        s0 += A0[k] * bv; s1 += A1[k] * bv; s2 += A2[k] * bv; s3 += A3[k] * bv;
    }
    float bb = bias[n];
    C[(size_t)(mg * 4 + 0) * ldc + n] = s0 + bb;
    C[(size_t)(mg * 4 + 1) * ldc + n] = s1 + bb;
    C[(size_t)(mg * 4 + 2) * ldc + n] = s2 + bb;
    C[(size_t)(mg * 4 + 3) * ldc + n] = s3 + bb;
}

// ---------------- Bahdanau attention + context + decoder input build ----------------
// One block per batch b. xt[b] = [ctx (1024), emb_fr[dec_in[b]] (256)]
__global__ __launch_bounds__(256) void attn_ctx(const float* __restrict__ qb,
                                                const float* __restrict__ enc_proj,
                                                const float* __restrict__ enc_out,
                                                const float* __restrict__ vvec,
                                                const float* __restrict__ vb,
                                                const float* __restrict__ emb_fr,
                                                const int* __restrict__ dec_in,
                                                float* __restrict__ xt) {
    int b = blockIdx.x;
    int tid = threadIdx.x;
    int wave = tid >> 6, lane = tid & 63;
    __shared__ float sc[SS];
    __shared__ float wsm[SS];
    const float* q = qb + (size_t)b * HH;
    for (int s = wave; s < SS; s += 4) {
        const float* ep = enc_proj + (size_t)(b * SS + s) * HH;
        float sum = 0.f;
        for (int h = lane; h < HH; h += 64)
            sum += tanhf(q[h] + ep[h]) * vvec[h];
#pragma unroll
        for (int o = 32; o; o >>= 1) sum += __shfl_xor(sum, o, 64);
        if (lane == 0) sc[s] = sum + vb[0];
    }
    __syncthreads();
    if (tid < 64) {
        float v = (lane < SS) ? sc[lane] : -3.4e38f;
        float m = v;
#pragma unroll
        for (int o = 32; o; o >>= 1) m = fmaxf(m, __shfl_xor(m, o, 64));
        float e = (lane < SS) ? expf(v - m) : 0.f;
        float ssum = e;
#pragma unroll
        for (int o = 32; o; o >>= 1) ssum += __shfl_xor(ssum, o, 64);
        if (lane < SS) wsm[lane] = e / ssum;
    }
    __syncthreads();
    for (int h = tid; h < HH; h += 256) {
        float cx = 0.f;
#pragma unroll 4
        for (int s = 0; s < SS; ++s)
            cx += wsm[s] * enc_out[(size_t)(b * SS + s) * HH + h];
        xt[(size_t)b * (HH + EE) + h] = cx;
    }
    {
        int tok = dec_in[b];
        xt[(size_t)b * (HH + EE) + HH + tid] = emb_fr[(size_t)tok * EE + tid];
    }
}

// ---------------- decoder init: out[:,0,:] one-hot, dec_in = start_id ----------------
__global__ __launch_bounds__(256) void init_dec(float* __restrict__ out,
                                                int* __restrict__ dec_in,
                                                const int* __restrict__ start_id) {
    int idx = blockIdx.x * 256 + threadIdx.x;   // < BB*VOC
    int sid = start_id[0];
    int b = idx / VOC, v = idx % VOC;
    out[(size_t)b * (GEN * VOC) + v] = (v == sid) ? 1.f : 0.f;
    if (blockIdx.x == 0 && threadIdx.x < BB) dec_in[threadIdx.x] = sid;
}

// ---------------- argmax over logits row (ties -> lowest index) ----------------
__global__ __launch_bounds__(256) void argmax_k(const float* __restrict__ logits,
                                                int ld, int* __restrict__ dec_in) {
    int b = blockIdx.x;
    int tid = threadIdx.x;
    const float* p = logits + (size_t)b * ld;
    __shared__ float sv[256];
    __shared__ int si[256];
    float best = -3.4e38f;
    int bi = 0;
    for (int v = tid; v < VOC; v += 256) {
        float x = p[v];
        if (x > best) { best = x; bi = v; }
    }
    sv[tid] = best; si[tid] = bi;
    __syncthreads();
    for (int s = 128; s; s >>= 1) {
        if (tid < s) {
            if (sv[tid + s] > sv[tid] ||
                (sv[tid + s] == sv[tid] && si[tid + s] < si[tid])) {
                sv[tid] = sv[tid + s]; si[tid] = si[tid + s];
            }
        }
        __syncthreads();
    }
    if (tid == 0) dec_in[b] = si[0];
}

extern "C" void kernel_launch(void* const* d_in, const int* in_sizes, int n_in,
                              void* d_out, int out_size, void* d_ws, size_t ws_size,
                              hipStream_t stream) {
    const int*   inputs   = (const int*)d_in[0];
    const int*   start_id = (const int*)d_in[2];
    const float* emb_en   = (const float*)d_in[3];
    const float* emb_fr   = (const float*)d_in[4];
    const float* enc_W0   = (const float*)d_in[5];
    const float* enc_U0   = (const float*)d_in[6];
    const float* enc_b0   = (const float*)d_in[7];
    const float* enc_W1   = (const float*)d_in[8];
    const float* enc_U1   = (const float*)d_in[9];
    const float* enc_b1   = (const float*)d_in[10];
    const float* dec_W0   = (const float*)d_in[11];
    const float* dec_b0   = (const float*)d_in[13];
    const float* dec_W1   = (const float*)d_in[14];
    const float* dec_b1   = (const float*)d_in[16];
    const float* attn_W1  = (const float*)d_in[17];
    const float* attn_b1  = (const float*)d_in[18];
    const float* attn_W2  = (const float*)d_in[19];
    const float* attn_b2  = (const float*)d_in[20];
    const float* attn_V   = (const float*)d_in[21];
    const float* attn_Vb  = (const float*)d_in[22];
    const float* fc_W     = (const float*)d_in[23];
    const float* fc_b     = (const float*)d_in[24];
    float* out = (float*)d_out;
    float* ws  = (float*)d_ws;

    // workspace carve (floats)
    float* giA   = ws;                       // BB*SS*G3 = 4,718,592
    float* x_emb = giA + (size_t)BB * SS * G3;        // 393,216
    float* seq0  = x_emb + (size_t)BB * SS * EE;      // 1,572,864
    float* encO  = seq0 + (size_t)BB * SS * HH;       // 1,572,864
    float* encP  = encO + (size_t)BB * SS * HH;       // 1,572,864
    float* hA    = encP + (size_t)BB * SS * HH;       // 32,768
    float* hB    = hA + BB * HH;                      // 32,768
    float* qbuf  = hB + BB * HH;                      // 32,768
    float* xt    = qbuf + BB * HH;                    // 40,960
    float* h1    = xt + BB * (HH + EE);               // 32,768
    int*   dec_in = (int*)(h1 + BB * HH);             // 32 ints

    // ---- encoder ----
    embed_en_k<<<(BB * SS * EE) / 256, 256, 0, stream>>>(inputs, emb_en, x_emb);
    gemm_tiled<<<dim3(G3 / 64, (BB * SS) / 64), 256, 0, stream>>>(
        x_emb, enc_W0, enc_b0, giA, BB * SS, G3, EE);
    hipMemsetAsync(hA, 0, 2 * BB * HH * sizeof(float), stream);
    for (int t = 0; t < SS; ++t) {
        const float* hin = (t & 1) ? hB : hA;
        float* hout = (t & 1) ? hA : hB;
        enc_gru_step<<<HH / 8, 384, 0, stream>>>(giA, enc_U0, enc_b0 + G3, hin, hout, seq0, t);
    }
    gemm_tiled<<<dim3(G3 / 64, (BB * SS) / 64), 256, 0, stream>>>(
        seq0, enc_W1, enc_b1, giA, BB * SS, G3, HH);
    hipMemsetAsync(hA, 0, 2 * BB * HH * sizeof(float), stream);
    for (int t = 0; t < SS; ++t) {
        const float* hin = (t & 1) ? hB : hA;
        float* hout = (t & 1) ? hA : hB;
        enc_gru_step<<<HH / 8, 384, 0, stream>>>(giA, enc_U1, enc_b1 + G3, hin, hout, encO, t);
    }
    // final hidden state now in hA (t=47 odd writes hA)
    gemm_tiled<<<dim3(HH / 64, (BB * SS) / 64), 256, 0, stream>>>(
        encO, attn_W2, attn_b2, encP, BB * SS, HH, HH);

    // ---- decoder ----
    init_dec<<<(BB * VOC) / 256, 256, 0, stream>>>(out, dec_in, start_id);
    for (int step = 1; step < GEN; ++step) {
        gemm_smallM<<<HH / 32, 256, 0, stream>>>(hA, attn_W1, attn_b1, qbuf, HH, HH, HH);
        attn_ctx<<<BB, 256, 0, stream>>>(qbuf, encP, encO, attn_V, attn_Vb, emb_fr, dec_in, xt);
        dec_gru_fused<<<HH / 8, 768, 0, stream>>>(xt, HH + EE, dec_W0, dec_b0, dec_b0 + G3, h1);
        dec_gru_fused<<<HH / 8, 768, 0, stream>>>(h1, HH, dec_W1, dec_b1, dec_b1 + G3, hA);
        gemm_smallM<<<VOC / 32, 256, 0, stream>>>(hA, fc_W, fc_b, out + (size_t)step * VOC,
                                                  HH, VOC, GEN * VOC);
        if (step < GEN - 1)
            argmax_k<<<BB, 256, 0, stream>>>(out + (size_t)step * VOC, GEN * VOC, dec_in);
    }
}